// Round 9
// baseline (303.441 us; speedup 1.0000x reference)
//
#include <hip/hip_runtime.h>
#include <hip/hip_bf16.h>
#include <math.h>

typedef __bf16 bf16_t;
typedef __bf16 bf16x8 __attribute__((ext_vector_type(8)));
typedef float f32x4 __attribute__((ext_vector_type(4)));

// ---------------- helpers ----------------

__device__ __forceinline__ void g2l16(const bf16_t* g, bf16_t* l) {
  __builtin_amdgcn_global_load_lds(
      (const __attribute__((address_space(1))) void*)g,
      (__attribute__((address_space(3))) void*)l, 16, 0, 0);
}

// T1: bijective XCD-chunked block remap (requires total wgs % 8 == 0)
__device__ __forceinline__ void xcdswz(int& bx, int& by, int& bz) {
  const int gx = gridDim.x, gy = gridDim.y;
  const int n = gx * gy * gridDim.z;
  int f = bx + gx * (by + gy * bz);
  const int cpx = n >> 3;
  int s = (f & 7) * cpx + (f >> 3);
  bx = s % gx; s /= gx; by = s % gy; bz = s / gy;
}

// swizzled LDS fragment read: row-major [*][64] bf16 tile, byte ^= (row&7)<<4
__device__ __forceinline__ bf16x8 rdf(const char* base, int row, int kbyte) {
  int off = (row << 7) + kbyte;
  off ^= (row & 7) << 4;
  return *reinterpret_cast<const bf16x8*>(base + off);
}

// ---------------- casts fp32 -> bf16 ----------------

__global__ __launch_bounds__(256) void cast_f32_to_bf16(
    const float* __restrict__ in, bf16_t* __restrict__ out, long n) {
  long i = ((long)blockIdx.x * 256 + threadIdx.x) * 8;
  if (i >= n) return;
  float4 a = *reinterpret_cast<const float4*>(in + i);
  float4 b = *reinterpret_cast<const float4*>(in + i + 4);
  bf16x8 o;
  o[0] = (bf16_t)a.x; o[1] = (bf16_t)a.y; o[2] = (bf16_t)a.z; o[3] = (bf16_t)a.w;
  o[4] = (bf16_t)b.x; o[5] = (bf16_t)b.y; o[6] = (bf16_t)b.z; o[7] = (bf16_t)b.w;
  *reinterpret_cast<bf16x8*>(out + i) = o;
}

// 4 weight matrices (each 1048576 elems) in one dispatch; 512 blocks each
__global__ __launch_bounds__(256) void cast_w4(
    const float* __restrict__ w0, const float* __restrict__ w1,
    const float* __restrict__ w2, const float* __restrict__ w3,
    bf16_t* __restrict__ o0, bf16_t* __restrict__ o1,
    bf16_t* __restrict__ o2, bf16_t* __restrict__ o3) {
  const int sel = blockIdx.x >> 9;
  const int blk = blockIdx.x & 511;
  const float* in = sel == 0 ? w0 : (sel == 1 ? w1 : (sel == 2 ? w2 : w3));
  bf16_t* out = sel == 0 ? o0 : (sel == 1 ? o1 : (sel == 2 ? o2 : o3));
  long i = ((long)blk * 256 + threadIdx.x) * 8;
  float4 a = *reinterpret_cast<const float4*>(in + i);
  float4 b = *reinterpret_cast<const float4*>(in + i + 4);
  bf16x8 o;
  o[0] = (bf16_t)a.x; o[1] = (bf16_t)a.y; o[2] = (bf16_t)a.z; o[3] = (bf16_t)a.w;
  o[4] = (bf16_t)b.x; o[5] = (bf16_t)b.y; o[6] = (bf16_t)b.z; o[7] = (bf16_t)b.w;
  *reinterpret_cast<bf16x8*>(out + i) = o;
}

// ============ 256x256 8-phase GEMM (m201-style template, plain HIP) ============
// C[m,n] = alpha * sum_k A[m,k]*B[n,k]; A:(M,K), B:(N,K) row-major bf16, K%128==0.
// 8 waves (512 thr), BK=64, 2x LDS dbuf (128 KiB), st-swizzle byte^=(row&7)<<4,
// deep staging + counted vmcnt.
// EPI: 1 = QKV split: col>>10 selects {C0,C1,C2} bf16 (row stride 1024) + bias.
//      3 = fp32 out = s + bias0[col] to C0, row length Ncols.

#define STAGE256(d, o, h, t) do {                                              \
  const bf16_t* gsrc_ = ((o) ? Bb : Ab) + (long)((h) * 128 + srl) * K +        \
                        (long)(t) * 64 + sgsw;                                 \
  bf16_t* ldsb_ = &lds[d][o][(h) * 8192] + ldst;                               \
  g2l16(gsrc_, ldsb_);                                                         \
  g2l16(gsrc_ + 64L * K, ldsb_ + 4096);                                        \
} while (0)

#define AREAD256(d, qm) do {                                                   \
  const char* Ab_ = (const char*)&lds[d][0][0];                                \
  int r_ = (qm) * 128 + wr2 * 64 + rA;                                         \
  a0 = rdf(Ab_, r_, kb);      a1 = rdf(Ab_, r_, kb + 64);                      \
  a2 = rdf(Ab_, r_ + 16, kb); a3 = rdf(Ab_, r_ + 16, kb + 64);                 \
  a4 = rdf(Ab_, r_ + 32, kb); a5 = rdf(Ab_, r_ + 32, kb + 64);                 \
  a6 = rdf(Ab_, r_ + 48, kb); a7 = rdf(Ab_, r_ + 48, kb + 64);                 \
} while (0)

#define BREAD256(d, qn, r0v, r1v, r2v, r3v) do {                               \
  const char* Bb_ = (const char*)&lds[d][1][0];                                \
  int c_ = (qn) * 128 + wc2 * 32 + rA;                                         \
  r0v = rdf(Bb_, c_, kb);      r1v = rdf(Bb_, c_, kb + 64);                    \
  r2v = rdf(Bb_, c_ + 16, kb); r3v = rdf(Bb_, c_ + 16, kb + 64);               \
} while (0)

#define MFMA16(qm, qn, b0v, b1v, b2v, b3v) do {                                \
  acc[(qm)*4+0][(qn)*2+0] = __builtin_amdgcn_mfma_f32_16x16x32_bf16(a0, b0v, acc[(qm)*4+0][(qn)*2+0], 0,0,0); \
  acc[(qm)*4+0][(qn)*2+0] = __builtin_amdgcn_mfma_f32_16x16x32_bf16(a1, b1v, acc[(qm)*4+0][(qn)*2+0], 0,0,0); \
  acc[(qm)*4+1][(qn)*2+0] = __builtin_amdgcn_mfma_f32_16x16x32_bf16(a2, b0v, acc[(qm)*4+1][(qn)*2+0], 0,0,0); \
  acc[(qm)*4+1][(qn)*2+0] = __builtin_amdgcn_mfma_f32_16x16x32_bf16(a3, b1v, acc[(qm)*4+1][(qn)*2+0], 0,0,0); \
  acc[(qm)*4+2][(qn)*2+0] = __builtin_amdgcn_mfma_f32_16x16x32_bf16(a4, b0v, acc[(qm)*4+2][(qn)*2+0], 0,0,0); \
  acc[(qm)*4+2][(qn)*2+0] = __builtin_amdgcn_mfma_f32_16x16x32_bf16(a5, b1v, acc[(qm)*4+2][(qn)*2+0], 0,0,0); \
  acc[(qm)*4+3][(qn)*2+0] = __builtin_amdgcn_mfma_f32_16x16x32_bf16(a6, b0v, acc[(qm)*4+3][(qn)*2+0], 0,0,0); \
  acc[(qm)*4+3][(qn)*2+0] = __builtin_amdgcn_mfma_f32_16x16x32_bf16(a7, b1v, acc[(qm)*4+3][(qn)*2+0], 0,0,0); \
  acc[(qm)*4+0][(qn)*2+1] = __builtin_amdgcn_mfma_f32_16x16x32_bf16(a0, b2v, acc[(qm)*4+0][(qn)*2+1], 0,0,0); \
  acc[(qm)*4+0][(qn)*2+1] = __builtin_amdgcn_mfma_f32_16x16x32_bf16(a1, b3v, acc[(qm)*4+0][(qn)*2+1], 0,0,0); \
  acc[(qm)*4+1][(qn)*2+1] = __builtin_amdgcn_mfma_f32_16x16x32_bf16(a2, b2v, acc[(qm)*4+1][(qn)*2+1], 0,0,0); \
  acc[(qm)*4+1][(qn)*2+1] = __builtin_amdgcn_mfma_f32_16x16x32_bf16(a3, b3v, acc[(qm)*4+1][(qn)*2+1], 0,0,0); \
  acc[(qm)*4+2][(qn)*2+1] = __builtin_amdgcn_mfma_f32_16x16x32_bf16(a4, b2v, acc[(qm)*4+2][(qn)*2+1], 0,0,0); \
  acc[(qm)*4+2][(qn)*2+1] = __builtin_amdgcn_mfma_f32_16x16x32_bf16(a5, b3v, acc[(qm)*4+2][(qn)*2+1], 0,0,0); \
  acc[(qm)*4+3][(qn)*2+1] = __builtin_amdgcn_mfma_f32_16x16x32_bf16(a6, b2v, acc[(qm)*4+3][(qn)*2+1], 0,0,0); \
  acc[(qm)*4+3][(qn)*2+1] = __builtin_amdgcn_mfma_f32_16x16x32_bf16(a7, b3v, acc[(qm)*4+3][(qn)*2+1], 0,0,0); \
} while (0)

#define VMC(n) asm volatile("s_waitcnt vmcnt(" #n ")" ::: "memory")

#define PH_ENTER() do {                                                        \
  __builtin_amdgcn_s_barrier();                                                \
  asm volatile("s_waitcnt lgkmcnt(0)" ::: "memory");                           \
  __builtin_amdgcn_s_setprio(1);                                               \
} while (0)

#define PH_EXIT() do {                                                         \
  __builtin_amdgcn_s_setprio(0);                                               \
  __builtin_amdgcn_s_barrier();                                                \
} while (0)

template <int EPI>
__launch_bounds__(512, 2)
__global__ void gemm256(const bf16_t* __restrict__ A, const bf16_t* __restrict__ B,
                        int K, float alpha,
                        void* __restrict__ C0, void* __restrict__ C1, void* __restrict__ C2,
                        const float* __restrict__ bias0, const float* __restrict__ bias1,
                        const float* __restrict__ bias2,
                        int Ncols, long sA, long sB, long sC) {
  __shared__ bf16_t lds[2][2][16384];  // [dbuf][A/B][256*64] = 128 KiB

  int bx = blockIdx.x, by = blockIdx.y, bz = blockIdx.z;
  xcdswz(bx, by, bz);

  const int tid = threadIdx.x;
  const int lane = tid & 63;
  const int w = tid >> 6;
  const int wr2 = w >> 2;   // 0..1
  const int wc2 = w & 3;    // 0..3
  const int rA = lane & 15;
  const int kb = (lane >> 4) << 4;   // k-byte base within 128B row

  const int bm = bx * 256;
  const int bn = by * 256;
  const bf16_t* Ab = A + (long)bz * sA + (long)bm * K;
  const bf16_t* Bb = B + (long)bz * sB + (long)bn * K;

  // staging coords: thread covers 16B granule sgr of row srl (and srl+64)
  const int srl = tid >> 3;                      // 0..63
  const int sgr = tid & 7;                       // granule
  const int sgsw = (sgr ^ (srl & 7)) * 8;        // pre-swizzled src k-elem offset
  const int ldst = srl * 64 + sgr * 8;           // linear LDS dest (elems)

  f32x4 acc[8][4] = {};
  bf16x8 a0, a1, a2, a3, a4, a5, a6, a7;
  bf16x8 p0, p1, p2, p3, q0, q1, q2, q3;

  const int NT = K >> 6;  // K-tiles of 64 (even, >=4)

  // ---- prologue: full tile0 -> buf0, full tile1 -> buf1 ----
  STAGE256(0, 0, 0, 0);  // a: buf0.A0
  STAGE256(0, 1, 0, 0);  // b: buf0.B0
  STAGE256(0, 1, 1, 0);  // c: buf0.B1
  STAGE256(0, 0, 1, 0);  // d: buf0.A1
  STAGE256(1, 0, 0, 1);  // e: buf1.A0
  STAGE256(1, 1, 0, 1);  // f: buf1.B0
  STAGE256(1, 1, 1, 1);  // g: buf1.B1
  STAGE256(1, 0, 1, 1);  // h: buf1.A1
  VMC(12);               // retire a,b (needed ph1)
  __builtin_amdgcn_s_barrier();

  // ---- main loop: 2 K-tiles (t, t+1) per iteration, 8 phases ----
  int t = 0;
  for (int it = 0; it < NT / 2 - 1; ++it, t += 2) {
    // ph1
    AREAD256(0, 0); BREAD256(0, 0, p0, p1, p2, p3);
    VMC(10);
    PH_ENTER(); MFMA16(0, 0, p0, p1, p2, p3); PH_EXIT();
    // ph2
    BREAD256(0, 1, q0, q1, q2, q3);
    STAGE256(0, 0, 0, t + 2); STAGE256(0, 1, 0, t + 2);
    VMC(12);
    PH_ENTER(); MFMA16(0, 1, q0, q1, q2, q3); PH_EXIT();
    // ph3
    AREAD256(0, 1);
    STAGE256(0, 1, 1, t + 2);
    PH_ENTER(); MFMA16(1, 0, p0, p1, p2, p3); PH_EXIT();
    // ph4
    STAGE256(0, 0, 1, t + 2);
    VMC(12);
    PH_ENTER(); MFMA16(1, 1, q0, q1, q2, q3); PH_EXIT();
    // ph5
    AREAD256(1, 0); BREAD256(1, 0, p0, p1, p2, p3);
    VMC(10);
    PH_ENTER(); MFMA16(0, 0, p0, p1, p2, p3); PH_EXIT();
    // ph6
    BREAD256(1, 1, q0, q1, q2, q3);
    STAGE256(1, 0, 0, t + 3); STAGE256(1, 1, 0, t + 3);
    VMC(12);
    PH_ENTER(); MFMA16(0, 1, q0, q1, q2, q3); PH_EXIT();
    // ph7
    AREAD256(1, 1);
    STAGE256(1, 1, 1, t + 3);
    PH_ENTER(); MFMA16(1, 0, p0, p1, p2, p3); PH_EXIT();
    // ph8
    STAGE256(1, 0, 1, t + 3);
    VMC(12);
    PH_ENTER(); MFMA16(1, 1, q0, q1, q2, q3); PH_EXIT();
  }

  // ---- peeled final iteration (tiles NT-2, NT-1): no stages, drain gates ----
  AREAD256(0, 0); BREAD256(0, 0, p0, p1, p2, p3);
  VMC(10);
  PH_ENTER(); MFMA16(0, 0, p0, p1, p2, p3); PH_EXIT();
  BREAD256(0, 1, q0, q1, q2, q3);
  VMC(8);
  PH_ENTER(); MFMA16(0, 1, q0, q1, q2, q3); PH_EXIT();
  AREAD256(0, 1);
  PH_ENTER(); MFMA16(1, 0, p0, p1, p2, p3); PH_EXIT();
  VMC(4);
  PH_ENTER(); MFMA16(1, 1, q0, q1, q2, q3); PH_EXIT();
  AREAD256(1, 0); BREAD256(1, 0, p0, p1, p2, p3);
  VMC(2);
  PH_ENTER(); MFMA16(0, 0, p0, p1, p2, p3); PH_EXIT();
  BREAD256(1, 1, q0, q1, q2, q3);
  VMC(0);
  PH_ENTER(); MFMA16(0, 1, q0, q1, q2, q3); PH_EXIT();
  AREAD256(1, 1);
  PH_ENTER(); MFMA16(1, 0, p0, p1, p2, p3); PH_EXIT();
  PH_ENTER(); MFMA16(1, 1, q0, q1, q2, q3); PH_EXIT();

  // ---- epilogue: C/D layout col=lane&15, row=(lane>>4)*4+j ----
  const int rr = (lane >> 4) * 4;
  const int cc = lane & 15;
#pragma unroll
  for (int qm = 0; qm < 2; ++qm)
#pragma unroll
    for (int m = 0; m < 4; ++m) {
      const int grow = bm + qm * 128 + wr2 * 64 + m * 16 + rr;
#pragma unroll
      for (int qn = 0; qn < 2; ++qn)
#pragma unroll
        for (int n = 0; n < 2; ++n) {
          const int gcol = bn + qn * 128 + wc2 * 32 + n * 16 + cc;
          const f32x4 v = acc[qm * 4 + m][qn * 2 + n];
          if (EPI == 1) {
            const int sel = gcol >> 10;
            const int lcol = gcol & 1023;
            const float* bp = sel == 0 ? bias0 : (sel == 1 ? bias1 : bias2);
            bf16_t* op = sel == 0 ? (bf16_t*)C0 : (sel == 1 ? (bf16_t*)C1 : (bf16_t*)C2);
            const float bv = bp[lcol];
#pragma unroll
            for (int j = 0; j < 4; ++j)
              op[(long)(grow + j) * 1024 + lcol] = (bf16_t)(v[j] + bv);
          } else {  // EPI == 3: fp32 out + bias
            float* C = (float*)C0;
            const float bv = bias0[gcol];
#pragma unroll
            for (int j = 0; j < 4; ++j)
              C[(long)(grow + j) * Ncols + gcol] = v[j] + bv;
          }
        }
    }
  (void)Ncols; (void)sC;
}

// ---------------- 128x128 GEMM (m97-structure) for scores / ctx ----------------
// EXPO=1: store bf16(exp(alpha*acc)) (no bias) — scores P' epilogue.

template <int OUT_BF16, int HAS_BIAS, int EXPO>
__launch_bounds__(256, 2)
__global__ void gemm_bt(const bf16_t* __restrict__ A, const bf16_t* __restrict__ B,
                        const float* __restrict__ bias, void* __restrict__ Cv,
                        int M, int N, int K, float alpha,
                        long sA, long sB, long sC) {
  int bxi = blockIdx.x, byi = blockIdx.y, bzi = blockIdx.z;
  xcdswz(bxi, byi, bzi);
  const bf16_t* Ab = A + (long)bzi * sA;
  const bf16_t* Bb = B + (long)bzi * sB;
  const int bm = bxi * 128;
  const int bn = byi * 128;

  __shared__ bf16_t sAt[128 * 32];
  __shared__ bf16_t sBt[128 * 32];

  const int tid = threadIdx.x;
  const int lane = tid & 63;
  const int w = tid >> 6;
  const int wr = (w >> 1) * 64;
  const int wc = (w & 1) * 64;

  f32x4 acc[4][4] = {};

  const int r0 = tid >> 2;
  const int c0 = (tid & 3) * 8;
  const int r1 = 64 + (tid >> 2);
  const long lds0 = (long)tid * 8;
  const long lds1 = 2048 + (long)tid * 8;

  const int arow = wr + (lane & 15);
  const int brow = wc + (lane & 15);
  const int koff = (lane >> 4) * 8;

  const int nK = K >> 5;
  for (int kt = 0; kt < nK; ++kt) {
    const int k0 = kt << 5;
    g2l16(Ab + (long)(bm + r0) * K + k0 + c0, sAt + lds0);
    g2l16(Ab + (long)(bm + r1) * K + k0 + c0, sAt + lds1);
    g2l16(Bb + (long)(bn + r0) * K + k0 + c0, sBt + lds0);
    g2l16(Bb + (long)(bn + r1) * K + k0 + c0, sBt + lds1);
    __syncthreads();

    bf16x8 af[4], bfr[4];
#pragma unroll
    for (int m = 0; m < 4; ++m)
      af[m] = *reinterpret_cast<const bf16x8*>(sAt + (arow + m * 16) * 32 + koff);
#pragma unroll
    for (int n = 0; n < 4; ++n)
      bfr[n] = *reinterpret_cast<const bf16x8*>(sBt + (brow + n * 16) * 32 + koff);
#pragma unroll
    for (int m = 0; m < 4; ++m)
#pragma unroll
      for (int n = 0; n < 4; ++n)
        acc[m][n] = __builtin_amdgcn_mfma_f32_16x16x32_bf16(af[m], bfr[n], acc[m][n], 0, 0, 0);
    __syncthreads();
  }

  const int rbase = bm + wr + (lane >> 4) * 4;
  const int cbase = bn + wc + (lane & 15);
#pragma unroll
  for (int n = 0; n < 4; ++n) {
    const int col = cbase + n * 16;
    float bv = 0.f;
    if (HAS_BIAS) bv = bias[col];
#pragma unroll
    for (int m = 0; m < 4; ++m) {
      const int row0 = rbase + m * 16;
#pragma unroll
      for (int j = 0; j < 4; ++j) {
        float v = acc[m][n][j] * alpha + bv;
        if (EXPO) {
          bf16_t* C = (bf16_t*)Cv + (long)bzi * sC;
          C[(long)(row0 + j) * N + col] = (bf16_t)__expf(v);
        } else if (OUT_BF16) {
          bf16_t* C = (bf16_t*)Cv + (long)bzi * sC;
          C[(long)(row0 + j) * N + col] = (bf16_t)v;
        } else {
          float* C = (float*)Cv + (long)bzi * sC;
          C[(long)(row0 + j) * N + col] = v;
        }
      }
    }
  }
}

// ---------------- column partial sums of P'[b][q][k] over q ----------------
// grid (8 kc, 8 qc, 4 b); part[b][qc][k] = sum over 256 q-rows of chunk qc.

__global__ __launch_bounds__(256) void col_partial(const bf16_t* __restrict__ P,
                                                   float* __restrict__ part) {
  const int kc = blockIdx.x, qc = blockIdx.y, b = blockIdx.z;
  const int t = threadIdx.x;
  const int tk = t & 31;   // k-octet within 256-col chunk
  const int tq = t >> 5;   // 0..7
  const bf16_t* base = P + ((long)b * 2048 + (long)qc * 256 + tq) * 2048 + kc * 256 + tk * 8;
  float s[8] = {};
  for (int q = 0; q < 256; q += 8) {
    bf16x8 v = *reinterpret_cast<const bf16x8*>(base + (long)q * 2048);
#pragma unroll
    for (int u = 0; u < 8; ++u) s[u] += (float)v[u];
  }
  __shared__ float red[8][256];
#pragma unroll
  for (int u = 0; u < 8; ++u) red[tq][tk * 8 + u] = s[u];
  __syncthreads();
  float tot = 0.f;
#pragma unroll
  for (int r = 0; r < 8; ++r) tot += red[r][t];
  part[((long)b * 8 + qc) * 2048 + kc * 256 + t] = tot;
}

// ---------------- V scale+transpose: VsT[b][d][k] = V[b][k][d] / colsum[b][k] ----------------

__global__ __launch_bounds__(256) void vscale_T(const bf16_t* __restrict__ V,
                                                const float* __restrict__ part,
                                                bf16_t* __restrict__ VsT) {
  const int b = blockIdx.z;
  const int r0 = blockIdx.x * 64;   // k range
  const int c0 = blockIdx.y * 64;   // d range
  __shared__ bf16_t tile[64][72];
  const int t = threadIdx.x;
  const int i = t >> 2;
  const int cj = (t & 3) * 16;
  const int k = r0 + i;
  float rs = 0.f;
#pragma unroll
  for (int r = 0; r < 8; ++r) rs += part[((long)b * 8 + r) * 2048 + k];
  const float ri = 1.0f / rs;
  const bf16_t* src = V + ((long)b * 2048 + k) * 1024 + c0 + cj;
  bf16x8 a0 = *reinterpret_cast<const bf16x8*>(src);
  bf16x8 a1 = *reinterpret_cast<const bf16x8*>(src + 8);
#pragma unroll
  for (int u = 0; u < 8; ++u) {
    tile[i][cj + u] = (bf16_t)((float)a0[u] * ri);
    tile[i][cj + 8 + u] = (bf16_t)((float)a1[u] * ri);
  }
  __syncthreads();
  const int j = t >> 2;            // local d row
  const int rc = (t & 3) * 16;     // k chunk
  bf16x8 o0, o1;
#pragma unroll
  for (int u = 0; u < 8; ++u) o0[u] = tile[rc + u][j];
#pragma unroll
  for (int u = 0; u < 8; ++u) o1[u] = tile[rc + 8 + u][j];
  bf16_t* dst = VsT + ((long)b * 1024 + c0 + j) * 2048 + r0 + rc;
  *reinterpret_cast<bf16x8*>(dst) = o0;
  *reinterpret_cast<bf16x8*>(dst + 8) = o1;
}

// ---------------- launch ----------------
// Workspace (bytes):
//   [  0, 16M) xb        -> VsT after QKV
//   [ 16, 22M) Wqkvb (3072x1024 bf16)
//   [ 22, 24M) Wob
//   [ 24, 40M) Qb        -> ctxb after scores
//   [ 40, 56M) Kb
//   [ 56, 72M) Vb
//   [ 72,104M) P' bf16 (exp(scores/32), [b][q][k])
//   [168M,+256K) part fp32 [4][8][2048]

extern "C" void kernel_launch(void* const* d_in, const int* in_sizes, int n_in,
                              void* d_out, int out_size, void* d_ws, size_t ws_size,
                              hipStream_t stream) {
  const float* x  = (const float*)d_in[0];
  const float* Wq = (const float*)d_in[1];
  const float* bq = (const float*)d_in[2];
  const float* Wk = (const float*)d_in[3];
  const float* bk = (const float*)d_in[4];
  const float* Wv = (const float*)d_in[5];
  const float* bv = (const float*)d_in[6];
  const float* Wo = (const float*)d_in[7];
  const float* bo = (const float*)d_in[8];
  float* out = (float*)d_out;
  char* ws = (char*)d_ws;

  const long MB = 1024L * 1024L;
  bf16_t* xb    = (bf16_t*)(ws + 0);
  bf16_t* Wqkvb = (bf16_t*)(ws + 16 * MB);
  bf16_t* Wob   = (bf16_t*)(ws + 22 * MB);
  bf16_t* Qb    = (bf16_t*)(ws + 24 * MB);
  bf16_t* Kb    = (bf16_t*)(ws + 40 * MB);
  bf16_t* Vb    = (bf16_t*)(ws + 56 * MB);
  bf16_t* Pp    = (bf16_t*)(ws + 72 * MB);
  float*  part  = (float*)(ws + 168 * MB);
  bf16_t* VsT   = (bf16_t*)(ws + 0);        // overlaps dead xb
  bf16_t* ctxb  = (bf16_t*)(ws + 24 * MB);  // overlaps dead Qb

  // 1) casts
  cast_f32_to_bf16<<<4096, 256, 0, stream>>>(x, xb, 8388608);
  cast_w4<<<2048, 256, 0, stream>>>(Wq, Wk, Wv, Wo,
                                    Wqkvb, Wqkvb + 1048576, Wqkvb + 2097152, Wob);

  // 2) fused QKV projection: (8192,3072) = xb @ Wqkv^T + b, split into Qb/Kb/Vb
  gemm256<1><<<dim3(32, 12, 1), 512, 0, stream>>>(
      xb, Wqkvb, 1024, 1.0f, Qb, Kb, Vb, bq, bk, bv, 3072, 0, 0, 0);

  // 3) P'[b][q][k] = exp((Q_b @ K_b^T)/32), bf16 — 128^2 gemm_bt, 1024 blocks = 4 exact rounds
  gemm_bt<1, 0, 1><<<dim3(16, 16, 4), 256, 0, stream>>>(
      Qb, Kb, nullptr, Pp, 2048, 2048, 1024, 0.03125f,
      2048L * 1024, 2048L * 1024, 2048L * 2048);

  // 4) softmax-over-q denominators: column partial sums of P'
  col_partial<<<dim3(8, 8, 4), 256, 0, stream>>>(Pp, part);

  // 5) VsT[b][d][k] = V[b][k][d] * rinv[b][k]  (normalization folded into V)
  vscale_T<<<dim3(32, 16, 4), 256, 0, stream>>>(Vb, part, VsT);

  // 6) ctx[b] (2048,1024) = P'_b (2048,2048) @ VsT_b(1024,2048)^T
  dim3 gctx(16, 8, 4);
  gemm_bt<1, 0, 0><<<gctx, 256, 0, stream>>>(Pp, VsT, nullptr, ctxb, 2048, 1024, 2048, 1.0f,
                                             2048L * 2048, 1024L * 2048, 2048L * 1024);

  // 7) out (8192,1024) fp32 = ctx @ Wo^T + bo  (256-tile, 128 blocks, 1 round)
  gemm256<3><<<dim3(32, 4, 1), 512, 0, stream>>>(
      ctxb, Wob, 1024, 1.0f, out, nullptr, nullptr, bo, nullptr, nullptr,
      1024, 0, 0, 0);

  (void)in_sizes; (void)n_in; (void)out_size; (void)ws_size;
}

// Round 10
// 295.658 us; speedup vs baseline: 1.0263x; 1.0263x over previous
//
#include <hip/hip_runtime.h>
#include <hip/hip_bf16.h>
#include <math.h>

typedef __bf16 bf16_t;
typedef __bf16 bf16x8 __attribute__((ext_vector_type(8)));
typedef float f32x4 __attribute__((ext_vector_type(4)));

// ---------------- helpers ----------------

__device__ __forceinline__ void g2l16(const bf16_t* g, bf16_t* l) {
  __builtin_amdgcn_global_load_lds(
      (const __attribute__((address_space(1))) void*)g,
      (__attribute__((address_space(3))) void*)l, 16, 0, 0);
}

// T1: bijective XCD-chunked block remap (requires total wgs % 8 == 0)
__device__ __forceinline__ void xcdswz(int& bx, int& by, int& bz) {
  const int gx = gridDim.x, gy = gridDim.y;
  const int n = gx * gy * gridDim.z;
  int f = bx + gx * (by + gy * bz);
  const int cpx = n >> 3;
  int s = (f & 7) * cpx + (f >> 3);
  bx = s % gx; s /= gx; by = s % gy; bz = s / gy;
}

// swizzled LDS fragment read: row-major [*][64] bf16 tile, byte ^= (row&7)<<4
__device__ __forceinline__ bf16x8 rdf(const char* base, int row, int kbyte) {
  int off = (row << 7) + kbyte;
  off ^= (row & 7) << 4;
  return *reinterpret_cast<const bf16x8*>(base + off);
}

// ---------------- fused prep: cast x, cast 4 weights, zero part ----------------
// grid 6152: [0,4096) x-cast; [4096,6144) weight casts; [6144,6152) zero part.

__global__ __launch_bounds__(256) void prep(
    const float* __restrict__ x, const float* __restrict__ w0,
    const float* __restrict__ w1, const float* __restrict__ w2,
    const float* __restrict__ w3,
    bf16_t* __restrict__ xb, bf16_t* __restrict__ o0, bf16_t* __restrict__ o1,
    bf16_t* __restrict__ o2, bf16_t* __restrict__ o3,
    float* __restrict__ part) {
  const int bx = blockIdx.x;
  const int t = threadIdx.x;
  if (bx < 4096) {
    long i = ((long)bx * 256 + t) * 8;
    float4 a = *reinterpret_cast<const float4*>(x + i);
    float4 b = *reinterpret_cast<const float4*>(x + i + 4);
    bf16x8 o;
    o[0] = (bf16_t)a.x; o[1] = (bf16_t)a.y; o[2] = (bf16_t)a.z; o[3] = (bf16_t)a.w;
    o[4] = (bf16_t)b.x; o[5] = (bf16_t)b.y; o[6] = (bf16_t)b.z; o[7] = (bf16_t)b.w;
    *reinterpret_cast<bf16x8*>(xb + i) = o;
  } else if (bx < 6144) {
    const int sel = (bx - 4096) >> 9;
    const int blk = (bx - 4096) & 511;
    const float* in = sel == 0 ? w0 : (sel == 1 ? w1 : (sel == 2 ? w2 : w3));
    bf16_t* out = sel == 0 ? o0 : (sel == 1 ? o1 : (sel == 2 ? o2 : o3));
    long i = ((long)blk * 256 + t) * 8;
    float4 a = *reinterpret_cast<const float4*>(in + i);
    float4 b = *reinterpret_cast<const float4*>(in + i + 4);
    bf16x8 o;
    o[0] = (bf16_t)a.x; o[1] = (bf16_t)a.y; o[2] = (bf16_t)a.z; o[3] = (bf16_t)a.w;
    o[4] = (bf16_t)b.x; o[5] = (bf16_t)b.y; o[6] = (bf16_t)b.z; o[7] = (bf16_t)b.w;
    *reinterpret_cast<bf16x8*>(out + i) = o;
  } else {
    // zero part[4][2048] (8192 floats): 8 blocks x 256 threads x 4 floats
    long i = ((long)(bx - 6144) * 256 + t) * 4;
    float4 z = {0.f, 0.f, 0.f, 0.f};
    *reinterpret_cast<float4*>(part + i) = z;
  }
}

// ============ 256x256 8-phase GEMM (m201-style template, plain HIP) ============
// C[m,n] = alpha * sum_k A[m,k]*B[n,k]; A:(M,K), B:(N,K) row-major bf16, K%128==0.
// 8 waves (512 thr), BK=64, 2x LDS dbuf (128 KiB), st-swizzle byte^=(row&7)<<4,
// deep staging + counted vmcnt.
// EPI: 1 = QKV split: col>>10 selects {C0,C1,C2} bf16 (row stride 1024) + bias.
//      3 = fp32 out = s + bias0[col] to C0, row length Ncols.

#define STAGE256(d, o, h, t) do {                                              \
  const bf16_t* gsrc_ = ((o) ? Bb : Ab) + (long)((h) * 128 + srl) * K +        \
                        (long)(t) * 64 + sgsw;                                 \
  bf16_t* ldsb_ = &lds[d][o][(h) * 8192] + ldst;                               \
  g2l16(gsrc_, ldsb_);                                                         \
  g2l16(gsrc_ + 64L * K, ldsb_ + 4096);                                        \
} while (0)

#define AREAD256(d, qm) do {                                                   \
  const char* Ab_ = (const char*)&lds[d][0][0];                                \
  int r_ = (qm) * 128 + wr2 * 64 + rA;                                         \
  a0 = rdf(Ab_, r_, kb);      a1 = rdf(Ab_, r_, kb + 64);                      \
  a2 = rdf(Ab_, r_ + 16, kb); a3 = rdf(Ab_, r_ + 16, kb + 64);                 \
  a4 = rdf(Ab_, r_ + 32, kb); a5 = rdf(Ab_, r_ + 32, kb + 64);                 \
  a6 = rdf(Ab_, r_ + 48, kb); a7 = rdf(Ab_, r_ + 48, kb + 64);                 \
} while (0)

#define BREAD256(d, qn, r0v, r1v, r2v, r3v) do {                               \
  const char* Bb_ = (const char*)&lds[d][1][0];                                \
  int c_ = (qn) * 128 + wc2 * 32 + rA;                                         \
  r0v = rdf(Bb_, c_, kb);      r1v = rdf(Bb_, c_, kb + 64);                    \
  r2v = rdf(Bb_, c_ + 16, kb); r3v = rdf(Bb_, c_ + 16, kb + 64);               \
} while (0)

#define MFMA16(qm, qn, b0v, b1v, b2v, b3v) do {                                \
  acc[(qm)*4+0][(qn)*2+0] = __builtin_amdgcn_mfma_f32_16x16x32_bf16(a0, b0v, acc[(qm)*4+0][(qn)*2+0], 0,0,0); \
  acc[(qm)*4+0][(qn)*2+0] = __builtin_amdgcn_mfma_f32_16x16x32_bf16(a1, b1v, acc[(qm)*4+0][(qn)*2+0], 0,0,0); \
  acc[(qm)*4+1][(qn)*2+0] = __builtin_amdgcn_mfma_f32_16x16x32_bf16(a2, b0v, acc[(qm)*4+1][(qn)*2+0], 0,0,0); \
  acc[(qm)*4+1][(qn)*2+0] = __builtin_amdgcn_mfma_f32_16x16x32_bf16(a3, b1v, acc[(qm)*4+1][(qn)*2+0], 0,0,0); \
  acc[(qm)*4+2][(qn)*2+0] = __builtin_amdgcn_mfma_f32_16x16x32_bf16(a4, b0v, acc[(qm)*4+2][(qn)*2+0], 0,0,0); \
  acc[(qm)*4+2][(qn)*2+0] = __builtin_amdgcn_mfma_f32_16x16x32_bf16(a5, b1v, acc[(qm)*4+2][(qn)*2+0], 0,0,0); \
  acc[(qm)*4+3][(qn)*2+0] = __builtin_amdgcn_mfma_f32_16x16x32_bf16(a6, b0v, acc[(qm)*4+3][(qn)*2+0], 0,0,0); \
  acc[(qm)*4+3][(qn)*2+0] = __builtin_amdgcn_mfma_f32_16x16x32_bf16(a7, b1v, acc[(qm)*4+3][(qn)*2+0], 0,0,0); \
  acc[(qm)*4+0][(qn)*2+1] = __builtin_amdgcn_mfma_f32_16x16x32_bf16(a0, b2v, acc[(qm)*4+0][(qn)*2+1], 0,0,0); \
  acc[(qm)*4+0][(qn)*2+1] = __builtin_amdgcn_mfma_f32_16x16x32_bf16(a1, b3v, acc[(qm)*4+0][(qn)*2+1], 0,0,0); \
  acc[(qm)*4+1][(qn)*2+1] = __builtin_amdgcn_mfma_f32_16x16x32_bf16(a2, b2v, acc[(qm)*4+1][(qn)*2+1], 0,0,0); \
  acc[(qm)*4+1][(qn)*2+1] = __builtin_amdgcn_mfma_f32_16x16x32_bf16(a3, b3v, acc[(qm)*4+1][(qn)*2+1], 0,0,0); \
  acc[(qm)*4+2][(qn)*2+1] = __builtin_amdgcn_mfma_f32_16x16x32_bf16(a4, b2v, acc[(qm)*4+2][(qn)*2+1], 0,0,0); \
  acc[(qm)*4+2][(qn)*2+1] = __builtin_amdgcn_mfma_f32_16x16x32_bf16(a5, b3v, acc[(qm)*4+2][(qn)*2+1], 0,0,0); \
  acc[(qm)*4+3][(qn)*2+1] = __builtin_amdgcn_mfma_f32_16x16x32_bf16(a6, b2v, acc[(qm)*4+3][(qn)*2+1], 0,0,0); \
  acc[(qm)*4+3][(qn)*2+1] = __builtin_amdgcn_mfma_f32_16x16x32_bf16(a7, b3v, acc[(qm)*4+3][(qn)*2+1], 0,0,0); \
} while (0)

#define VMC(n) asm volatile("s_waitcnt vmcnt(" #n ")" ::: "memory")

#define PH_ENTER() do {                                                        \
  __builtin_amdgcn_s_barrier();                                                \
  asm volatile("s_waitcnt lgkmcnt(0)" ::: "memory");                           \
  __builtin_amdgcn_s_setprio(1);                                               \
} while (0)

#define PH_EXIT() do {                                                         \
  __builtin_amdgcn_s_setprio(0);                                               \
  __builtin_amdgcn_s_barrier();                                                \
} while (0)

template <int EPI>
__launch_bounds__(512, 2)
__global__ void gemm256(const bf16_t* __restrict__ A, const bf16_t* __restrict__ B,
                        int K, float alpha,
                        void* __restrict__ C0, void* __restrict__ C1, void* __restrict__ C2,
                        const float* __restrict__ bias0, const float* __restrict__ bias1,
                        const float* __restrict__ bias2,
                        int Ncols, long sA, long sB, long sC) {
  __shared__ bf16_t lds[2][2][16384];  // [dbuf][A/B][256*64] = 128 KiB

  int bx = blockIdx.x, by = blockIdx.y, bz = blockIdx.z;
  xcdswz(bx, by, bz);

  const int tid = threadIdx.x;
  const int lane = tid & 63;
  const int w = tid >> 6;
  const int wr2 = w >> 2;   // 0..1
  const int wc2 = w & 3;    // 0..3
  const int rA = lane & 15;
  const int kb = (lane >> 4) << 4;   // k-byte base within 128B row

  const int bm = bx * 256;
  const int bn = by * 256;
  const bf16_t* Ab = A + (long)bz * sA + (long)bm * K;
  const bf16_t* Bb = B + (long)bz * sB + (long)bn * K;

  // staging coords: thread covers 16B granule sgr of row srl (and srl+64)
  const int srl = tid >> 3;                      // 0..63
  const int sgr = tid & 7;                       // granule
  const int sgsw = (sgr ^ (srl & 7)) * 8;        // pre-swizzled src k-elem offset
  const int ldst = srl * 64 + sgr * 8;           // linear LDS dest (elems)

  f32x4 acc[8][4] = {};
  bf16x8 a0, a1, a2, a3, a4, a5, a6, a7;
  bf16x8 p0, p1, p2, p3, q0, q1, q2, q3;

  const int NT = K >> 6;  // K-tiles of 64 (even, >=4)

  // ---- prologue: full tile0 -> buf0, full tile1 -> buf1 ----
  STAGE256(0, 0, 0, 0);  // a: buf0.A0
  STAGE256(0, 1, 0, 0);  // b: buf0.B0
  STAGE256(0, 1, 1, 0);  // c: buf0.B1
  STAGE256(0, 0, 1, 0);  // d: buf0.A1
  STAGE256(1, 0, 0, 1);  // e: buf1.A0
  STAGE256(1, 1, 0, 1);  // f: buf1.B0
  STAGE256(1, 1, 1, 1);  // g: buf1.B1
  STAGE256(1, 0, 1, 1);  // h: buf1.A1
  VMC(12);               // retire a,b (needed ph1)
  __builtin_amdgcn_s_barrier();

  // ---- main loop: 2 K-tiles (t, t+1) per iteration, 8 phases ----
  int t = 0;
  for (int it = 0; it < NT / 2 - 1; ++it, t += 2) {
    // ph1
    AREAD256(0, 0); BREAD256(0, 0, p0, p1, p2, p3);
    VMC(10);
    PH_ENTER(); MFMA16(0, 0, p0, p1, p2, p3); PH_EXIT();
    // ph2
    BREAD256(0, 1, q0, q1, q2, q3);
    STAGE256(0, 0, 0, t + 2); STAGE256(0, 1, 0, t + 2);
    VMC(12);
    PH_ENTER(); MFMA16(0, 1, q0, q1, q2, q3); PH_EXIT();
    // ph3
    AREAD256(0, 1);
    STAGE256(0, 1, 1, t + 2);
    PH_ENTER(); MFMA16(1, 0, p0, p1, p2, p3); PH_EXIT();
    // ph4
    STAGE256(0, 0, 1, t + 2);
    VMC(12);
    PH_ENTER(); MFMA16(1, 1, q0, q1, q2, q3); PH_EXIT();
    // ph5
    AREAD256(1, 0); BREAD256(1, 0, p0, p1, p2, p3);
    VMC(10);
    PH_ENTER(); MFMA16(0, 0, p0, p1, p2, p3); PH_EXIT();
    // ph6
    BREAD256(1, 1, q0, q1, q2, q3);
    STAGE256(1, 0, 0, t + 3); STAGE256(1, 1, 0, t + 3);
    VMC(12);
    PH_ENTER(); MFMA16(0, 1, q0, q1, q2, q3); PH_EXIT();
    // ph7
    AREAD256(1, 1);
    STAGE256(1, 1, 1, t + 3);
    PH_ENTER(); MFMA16(1, 0, p0, p1, p2, p3); PH_EXIT();
    // ph8
    STAGE256(1, 0, 1, t + 3);
    VMC(12);
    PH_ENTER(); MFMA16(1, 1, q0, q1, q2, q3); PH_EXIT();
  }

  // ---- peeled final iteration (tiles NT-2, NT-1): no stages, drain gates ----
  AREAD256(0, 0); BREAD256(0, 0, p0, p1, p2, p3);
  VMC(10);
  PH_ENTER(); MFMA16(0, 0, p0, p1, p2, p3); PH_EXIT();
  BREAD256(0, 1, q0, q1, q2, q3);
  VMC(8);
  PH_ENTER(); MFMA16(0, 1, q0, q1, q2, q3); PH_EXIT();
  AREAD256(0, 1);
  PH_ENTER(); MFMA16(1, 0, p0, p1, p2, p3); PH_EXIT();
  VMC(4);
  PH_ENTER(); MFMA16(1, 1, q0, q1, q2, q3); PH_EXIT();
  AREAD256(1, 0); BREAD256(1, 0, p0, p1, p2, p3);
  VMC(2);
  PH_ENTER(); MFMA16(0, 0, p0, p1, p2, p3); PH_EXIT();
  BREAD256(1, 1, q0, q1, q2, q3);
  VMC(0);
  PH_ENTER(); MFMA16(0, 1, q0, q1, q2, q3); PH_EXIT();
  AREAD256(1, 1);
  PH_ENTER(); MFMA16(1, 0, p0, p1, p2, p3); PH_EXIT();
  PH_ENTER(); MFMA16(1, 1, q0, q1, q2, q3); PH_EXIT();

  // ---- epilogue: C/D layout col=lane&15, row=(lane>>4)*4+j ----
  const int rr = (lane >> 4) * 4;
  const int cc = lane & 15;
#pragma unroll
  for (int qm = 0; qm < 2; ++qm)
#pragma unroll
    for (int m = 0; m < 4; ++m) {
      const int grow = bm + qm * 128 + wr2 * 64 + m * 16 + rr;
#pragma unroll
      for (int qn = 0; qn < 2; ++qn)
#pragma unroll
        for (int n = 0; n < 2; ++n) {
          const int gcol = bn + qn * 128 + wc2 * 32 + n * 16 + cc;
          const f32x4 v = acc[qm * 4 + m][qn * 2 + n];
          if (EPI == 1) {
            const int sel = gcol >> 10;
            const int lcol = gcol & 1023;
            const float* bp = sel == 0 ? bias0 : (sel == 1 ? bias1 : bias2);
            bf16_t* op = sel == 0 ? (bf16_t*)C0 : (sel == 1 ? (bf16_t*)C1 : (bf16_t*)C2);
            const float bv = bp[lcol];
#pragma unroll
            for (int j = 0; j < 4; ++j)
              op[(long)(grow + j) * 1024 + lcol] = (bf16_t)(v[j] + bv);
          } else {  // EPI == 3: fp32 out + bias
            float* C = (float*)C0;
            const float bv = bias0[gcol];
#pragma unroll
            for (int j = 0; j < 4; ++j)
              C[(long)(grow + j) * Ncols + gcol] = v[j] + bv;
          }
        }
    }
  (void)Ncols; (void)sC;
}

// ---------------- 128x128 GEMM (m97-structure) for scores / ctx ----------------
// EXPO=1: store bf16(exp(alpha*acc)) (no bias) AND atomically accumulate
// per-column sums into part[b][col] (softmax-over-q denominators).

template <int OUT_BF16, int HAS_BIAS, int EXPO>
__launch_bounds__(256, 2)
__global__ void gemm_bt(const bf16_t* __restrict__ A, const bf16_t* __restrict__ B,
                        const float* __restrict__ bias, void* __restrict__ Cv,
                        float* __restrict__ part,
                        int M, int N, int K, float alpha,
                        long sA, long sB, long sC) {
  int bxi = blockIdx.x, byi = blockIdx.y, bzi = blockIdx.z;
  xcdswz(bxi, byi, bzi);
  const bf16_t* Ab = A + (long)bzi * sA;
  const bf16_t* Bb = B + (long)bzi * sB;
  const int bm = bxi * 128;
  const int bn = byi * 128;

  __shared__ bf16_t sAt[128 * 32];
  __shared__ bf16_t sBt[128 * 32];

  const int tid = threadIdx.x;
  const int lane = tid & 63;
  const int w = tid >> 6;
  const int wr = (w >> 1) * 64;
  const int wc = (w & 1) * 64;

  f32x4 acc[4][4] = {};

  const int r0 = tid >> 2;
  const int c0 = (tid & 3) * 8;
  const int r1 = 64 + (tid >> 2);
  const long lds0 = (long)tid * 8;
  const long lds1 = 2048 + (long)tid * 8;

  const int arow = wr + (lane & 15);
  const int brow = wc + (lane & 15);
  const int koff = (lane >> 4) * 8;

  const int nK = K >> 5;
  for (int kt = 0; kt < nK; ++kt) {
    const int k0 = kt << 5;
    g2l16(Ab + (long)(bm + r0) * K + k0 + c0, sAt + lds0);
    g2l16(Ab + (long)(bm + r1) * K + k0 + c0, sAt + lds1);
    g2l16(Bb + (long)(bn + r0) * K + k0 + c0, sBt + lds0);
    g2l16(Bb + (long)(bn + r1) * K + k0 + c0, sBt + lds1);
    __syncthreads();

    bf16x8 af[4], bfr[4];
#pragma unroll
    for (int m = 0; m < 4; ++m)
      af[m] = *reinterpret_cast<const bf16x8*>(sAt + (arow + m * 16) * 32 + koff);
#pragma unroll
    for (int n = 0; n < 4; ++n)
      bfr[n] = *reinterpret_cast<const bf16x8*>(sBt + (brow + n * 16) * 32 + koff);
#pragma unroll
    for (int m = 0; m < 4; ++m)
#pragma unroll
      for (int n = 0; n < 4; ++n)
        acc[m][n] = __builtin_amdgcn_mfma_f32_16x16x32_bf16(af[m], bfr[n], acc[m][n], 0, 0, 0);
    __syncthreads();
  }

  const int rbase = bm + wr + (lane >> 4) * 4;
  const int cbase = bn + wc + (lane & 15);
#pragma unroll
  for (int n = 0; n < 4; ++n) {
    const int col = cbase + n * 16;
    float bv = 0.f;
    if (HAS_BIAS) bv = bias[col];
    float cs = 0.f;
#pragma unroll
    for (int m = 0; m < 4; ++m) {
      const int row0 = rbase + m * 16;
#pragma unroll
      for (int j = 0; j < 4; ++j) {
        float v = acc[m][n][j] * alpha + bv;
        if (EXPO) {
          bf16_t* C = (bf16_t*)Cv + (long)bzi * sC;
          float e = __expf(v);
          C[(long)(row0 + j) * N + col] = (bf16_t)e;
          cs += e;
        } else if (OUT_BF16) {
          bf16_t* C = (bf16_t*)Cv + (long)bzi * sC;
          C[(long)(row0 + j) * N + col] = (bf16_t)v;
        } else {
          float* C = (float*)Cv + (long)bzi * sC;
          C[(long)(row0 + j) * N + col] = v;
        }
      }
    }
    if (EXPO) {
      // fold the 4 row-lane-groups (lanes l, l+16, l+32, l+48 share col)
      cs += __shfl_down(cs, 32);
      cs += __shfl_down(cs, 16);
      if (lane < 16) atomicAdd(&part[(long)bzi * 2048 + col], cs);
    }
  }
}

// ---------------- V scale+transpose: VsT[b][d][k] = V[b][k][d] / part[b][k] ----------------

__global__ __launch_bounds__(256) void vscale_T(const bf16_t* __restrict__ V,
                                                const float* __restrict__ part,
                                                bf16_t* __restrict__ VsT) {
  const int b = blockIdx.z;
  const int r0 = blockIdx.x * 64;   // k range
  const int c0 = blockIdx.y * 64;   // d range
  __shared__ bf16_t tile[64][72];
  const int t = threadIdx.x;
  const int i = t >> 2;
  const int cj = (t & 3) * 16;
  const int k = r0 + i;
  const float ri = 1.0f / part[(long)b * 2048 + k];
  const bf16_t* src = V + ((long)b * 2048 + k) * 1024 + c0 + cj;
  bf16x8 a0 = *reinterpret_cast<const bf16x8*>(src);
  bf16x8 a1 = *reinterpret_cast<const bf16x8*>(src + 8);
#pragma unroll
  for (int u = 0; u < 8; ++u) {
    tile[i][cj + u] = (bf16_t)((float)a0[u] * ri);
    tile[i][cj + 8 + u] = (bf16_t)((float)a1[u] * ri);
  }
  __syncthreads();
  const int j = t >> 2;            // local d row
  const int rc = (t & 3) * 16;     // k chunk
  bf16x8 o0, o1;
#pragma unroll
  for (int u = 0; u < 8; ++u) o0[u] = tile[rc + u][j];
#pragma unroll
  for (int u = 0; u < 8; ++u) o1[u] = tile[rc + 8 + u][j];
  bf16_t* dst = VsT + ((long)b * 1024 + c0 + j) * 2048 + r0 + rc;
  *reinterpret_cast<bf16x8*>(dst) = o0;
  *reinterpret_cast<bf16x8*>(dst + 8) = o1;
}

// ---------------- launch ----------------
// Workspace (bytes):
//   [  0, 16M) xb        -> VsT after QKV
//   [ 16, 22M) Wqkvb (3072x1024 bf16)
//   [ 22, 24M) Wob
//   [ 24, 40M) Qb        -> ctxb after scores
//   [ 40, 56M) Kb
//   [ 56, 72M) Vb
//   [ 72,104M) P' bf16 (exp(scores/32), [b][q][k])
//   [168M,+32K) part fp32 [4][2048]

extern "C" void kernel_launch(void* const* d_in, const int* in_sizes, int n_in,
                              void* d_out, int out_size, void* d_ws, size_t ws_size,
                              hipStream_t stream) {
  const float* x  = (const float*)d_in[0];
  const float* Wq = (const float*)d_in[1];
  const float* bq = (const float*)d_in[2];
  const float* Wk = (const float*)d_in[3];
  const float* bk = (const float*)d_in[4];
  const float* Wv = (const float*)d_in[5];
  const float* bv = (const float*)d_in[6];
  const float* Wo = (const float*)d_in[7];
  const float* bo = (const float*)d_in[8];
  float* out = (float*)d_out;
  char* ws = (char*)d_ws;

  const long MB = 1024L * 1024L;
  bf16_t* xb    = (bf16_t*)(ws + 0);
  bf16_t* Wqkvb = (bf16_t*)(ws + 16 * MB);
  bf16_t* Wob   = (bf16_t*)(ws + 22 * MB);
  bf16_t* Qb    = (bf16_t*)(ws + 24 * MB);
  bf16_t* Kb    = (bf16_t*)(ws + 40 * MB);
  bf16_t* Vb    = (bf16_t*)(ws + 56 * MB);
  bf16_t* Pp    = (bf16_t*)(ws + 72 * MB);
  float*  part  = (float*)(ws + 168 * MB);
  bf16_t* VsT   = (bf16_t*)(ws + 0);        // overlaps dead xb
  bf16_t* ctxb  = (bf16_t*)(ws + 24 * MB);  // overlaps dead Qb

  // 1) fused prep: cast x + 4 weights, zero part
  prep<<<6152, 256, 0, stream>>>(x, Wq, Wk, Wv, Wo,
                                 xb, Wqkvb, Wqkvb + 1048576, Wqkvb + 2097152, Wob,
                                 part);

  // 2) fused QKV projection: (8192,3072) = xb @ Wqkv^T + b, split into Qb/Kb/Vb
  gemm256<1><<<dim3(32, 12, 1), 512, 0, stream>>>(
      xb, Wqkvb, 1024, 1.0f, Qb, Kb, Vb, bq, bk, bv, 3072, 0, 0, 0);

  // 3) P'[b][q][k] = exp((Q_b @ K_b^T)/32), bf16; epilogue atomically
  //    accumulates column sums into part[b][k]
  gemm_bt<1, 0, 1><<<dim3(16, 16, 4), 256, 0, stream>>>(
      Qb, Kb, nullptr, Pp, part, 2048, 2048, 1024, 0.03125f,
      2048L * 1024, 2048L * 1024, 2048L * 2048);

  // 4) VsT[b][d][k] = V[b][k][d] / part[b][k]  (normalization folded into V)
  vscale_T<<<dim3(32, 16, 4), 256, 0, stream>>>(Vb, part, VsT);

  // 5) ctx[b] (2048,1024) = P'_b (2048,2048) @ VsT_b(1024,2048)^T
  dim3 gctx(16, 8, 4);
  gemm_bt<1, 0, 0><<<gctx, 256, 0, stream>>>(Pp, VsT, nullptr, ctxb, nullptr,
                                             2048, 1024, 2048, 1.0f,
                                             2048L * 2048, 1024L * 2048, 2048L * 1024);

  // 6) out (8192,1024) fp32 = ctx @ Wo^T + bo  (256-tile, 128 blocks, 1 round)
  gemm256<3><<<dim3(32, 4, 1), 512, 0, stream>>>(
      ctxb, Wob, 1024, 1.0f, out, nullptr, nullptr, bo, nullptr, nullptr,
      1024, 0, 0, 0);

  (void)in_sizes; (void)n_in; (void)out_size; (void)ws_size;
}